// Round 1
// baseline (1422.023 us; speedup 1.0000x reference)
//
#include <hip/hip_runtime.h>
#include <math.h>

#define BB 64
#define SS 4096
// ws layout (float offsets)
#define OF_G    0              // 2*4*256*20 = 40960 floats
#define OF_BG   40960          // 80
#define OF_DIST 41056          // 64*40 = 2560
#define OF_HFIN 43616          // 64*20 = 1280
#define OF_X    45056          // 64*4096*80 = 20971520
#define WS_NEEDED_FLOATS (OF_X + (size_t)BB * SS * 80)

__device__ __forceinline__ float fast_rcp(float x) { return __builtin_amdgcn_rcpf(x); }
__device__ __forceinline__ float sigm_fast(float x) { return fast_rcp(1.0f + __expf(-x)); }
__device__ __forceinline__ float tanh_fast(float x) { return 1.0f - 2.0f * fast_rcp(1.0f + __expf(2.0f * x)); }
__device__ __forceinline__ float sigm_prec(float x) { return 1.0f / (1.0f + __expf(-x)); }

// ---------------- K0: G tables + combined bias + zero dist accumulator ----------
__global__ __launch_bounds__(256) void k_init(const float* __restrict__ pc_emb,
    const float* __restrict__ addr_emb, const float* __restrict__ enc_W,
    const float* __restrict__ b_ih, const float* __restrict__ b_hh,
    float* __restrict__ ws) {
  int gid = blockIdx.x * 256 + threadIdx.x;
  if (gid < 2048) {
    int t = gid >> 10;          // stream: 0=pc, 1=addr
    int i = (gid >> 8) & 3;     // byte position
    int byt = gid & 255;
    const float* tab = (t == 0 ? pc_emb : addr_emb) + (i * 256 + byt) * 20;
    float tv[20];
#pragma unroll
    for (int m = 0; m < 20; m++) tv[m] = tab[m];
    float* Grow = ws + OF_G + gid * 20;
#pragma unroll
    for (int j = 0; j < 20; j++) {
      float acc = 0.f;
#pragma unroll
      for (int m = 0; m < 20; m++) acc = fmaf(enc_W[j * 80 + i * 20 + m], tv[m], acc);
      Grow[j] = acc;
    }
  } else if (gid < 2048 + 80) {
    int g = gid - 2048;
    ws[OF_BG + g] = b_ih[g] + b_hh[g];
  } else if (gid < 2048 + 80 + 2560) {
    ws[OF_DIST + (gid - 2128)] = 0.f;
  }
}

// ---------------- K1: embed + encoder + X precompute + dist partial sums --------
__global__ __launch_bounds__(256) void k_embed(const int* __restrict__ inp,
    const float* __restrict__ enc_b, const float* __restrict__ W_ih,
    float* __restrict__ ws) {
  int b = blockIdx.x >> 4;
  int s = ((blockIdx.x & 15) << 8) + threadIdx.x;
  unsigned v0 = (unsigned)inp[(b * SS + s) * 2 + 0];
  unsigned v1 = (unsigned)inp[(b * SS + s) * 2 + 1];
  const float* G = ws + OF_G;
  float e[40];
#pragma unroll
  for (int t = 0; t < 2; t++) {
    unsigned v = (t == 0) ? v0 : v1;
    int by0 = (int)(v >> 24);
    int by1 = (int)((v >> 16) & 255u);
    int by2 = (int)((v >> 8) & 255u);
    int by3 = (int)(v & 255u);
    const float* G0 = G + ((t * 4 + 0) * 256 + by0) * 20;
    const float* G1 = G + ((t * 4 + 1) * 256 + by1) * 20;
    const float* G2 = G + ((t * 4 + 2) * 256 + by2) * 20;
    const float* G3 = G + ((t * 4 + 3) * 256 + by3) * 20;
#pragma unroll
    for (int j = 0; j < 20; j++) {
      float y = enc_b[j] + G0[j] + G1[j] + G2[j] + G3[j];
      e[t * 20 + j] = sigm_prec(y);
    }
  }
  // dist_vector partial: wave-reduce each of 40 dims, lane 0 atomics
#pragma unroll
  for (int d = 0; d < 40; d++) {
    float v = e[d];
#pragma unroll
    for (int off = 32; off; off >>= 1) v += __shfl_xor(v, off);
    if ((threadIdx.x & 63) == 0) atomicAdd(ws + OF_DIST + b * 40 + d, v);
  }
  // X = e @ W_ih.T + (b_ih + b_hh), stored as [b][s][j][q], gate g = q*20+j
  const float* bg = ws + OF_BG;
  size_t tok = (size_t)(b * SS + s);
  float4* Xp = (float4*)(ws + OF_X) + tok * 20;
#pragma unroll 2
  for (int j = 0; j < 20; j++) {
    float op[4];
#pragma unroll
    for (int q = 0; q < 4; q++) {
      int g = q * 20 + j;
      float acc = bg[g];
#pragma unroll
      for (int d = 0; d < 40; d++) acc = fmaf(W_ih[g * 40 + d], e[d], acc);
      op[q] = acc;
    }
    Xp[j] = make_float4(op[0], op[1], op[2], op[3]);
  }
}

// ---------------- K2: sequential LSTM, one wave per batch item ------------------
__global__ __launch_bounds__(64) void k_lstm(const float* __restrict__ h0,
    const float* __restrict__ c0, const float* __restrict__ W_hh,
    float* __restrict__ ws) {
  int b = blockIdx.x;
  int lane = threadIdx.x;
  int j = lane < 20 ? lane : 19;  // lanes >=20 mirror j=19 harmlessly
  float wi[20], wf[20], wg[20], wo[20];
#pragma unroll
  for (int m = 0; m < 20; m++) {
    wi[m] = W_hh[(0 * 20 + j) * 20 + m];
    wf[m] = W_hh[(1 * 20 + j) * 20 + m];
    wg[m] = W_hh[(2 * 20 + j) * 20 + m];
    wo[m] = W_hh[(3 * 20 + j) * 20 + m];
  }
  float h = h0[b * 20 + j];
  float c = c0[b * 20 + j];
  const float4* Xp = (const float4*)(ws + OF_X) + (size_t)b * SS * 20 + j;
  float4 xb[4];
#pragma unroll
  for (int p = 0; p < 4; p++) xb[p] = Xp[(size_t)p * 20];
  for (int s = 0; s < SS; s += 4) {
#pragma unroll
    for (int u = 0; u < 4; u++) {
      float4 x4 = xb[u];
      int sp = s + u + 4; if (sp > SS - 1) sp = SS - 1;
      xb[u] = Xp[(size_t)sp * 20];
      float gi = x4.x, gf = x4.y, gg = x4.z, go = x4.w;
#pragma unroll
      for (int m = 0; m < 20; m++) {
        float hm = __int_as_float(__builtin_amdgcn_readlane(__float_as_int(h), m));
        gi = fmaf(wi[m], hm, gi);
        gf = fmaf(wf[m], hm, gf);
        gg = fmaf(wg[m], hm, gg);
        go = fmaf(wo[m], hm, go);
      }
      c = fmaf(sigm_fast(gf), c, sigm_fast(gi) * tanh_fast(gg));
      h = sigm_fast(go) * tanh_fast(c);
    }
  }
  if (lane < 20) ws[OF_HFIN + b * 20 + j] = h;
}

// ---------------- K3: decoder heads + softmax over batch axis -------------------
__global__ __launch_bounds__(256) void k_dec(const float* __restrict__ dec_W,
    const float* __restrict__ dec_b, float* __restrict__ out,
    const float* __restrict__ ws) {
  int wid = blockIdx.x * 4 + (threadIdx.x >> 6);  // (k,v) pair id, 0..1023
  int lane = threadIdx.x & 63;                    // = batch index b
  int k = wid >> 8;
  int v = wid & 255;
  const float* hp = ws + OF_HFIN + lane * 20;
  const float* wp = dec_W + (k * 256 + v) * 20;
  float l = dec_b[k * 256 + v];
#pragma unroll
  for (int jj = 0; jj < 20; jj++) l = fmaf(hp[jj], wp[jj], l);
  float x = l / 0.001f;
  float mx = x;
#pragma unroll
  for (int off = 32; off; off >>= 1) mx = fmaxf(mx, __shfl_xor(mx, off));
  float ex = __expf(x - mx);
  float sm = ex;
#pragma unroll
  for (int off = 32; off; off >>= 1) sm += __shfl_xor(sm, off);
  float p = ex / sm;
  int oidx = (k * 64 + lane) * 256 + v;
  out[oidx] = p;            // probs
  out[65536 + oidx] = l;    // logits
}

// ---------------- K4: byte_e = probs @ addr_emb, encoder, MLP head --------------
__global__ __launch_bounds__(128) void k_freq(const float* __restrict__ addr_emb,
    const float* __restrict__ enc_W, const float* __restrict__ enc_b,
    const float* __restrict__ d1_W, const float* __restrict__ d1_b,
    const float* __restrict__ d2_W, const float* __restrict__ d2_b,
    float* __restrict__ out, const float* __restrict__ ws) {
  __shared__ float be[80];
  __shared__ float fr[60];
  __shared__ float r1[10];
  int b = blockIdx.x;
  int t = threadIdx.x;
  if (t < 80) {
    int k = t / 20, e2 = t % 20;
    const float* pp = out + (k * 64 + b) * 256;        // probs[k,0,b,:]
    const float* ap = addr_emb + (k * 256) * 20 + e2;
    float acc = 0.f;
    for (int v = 0; v < 256; v++) acc = fmaf(pp[v], ap[v * 20], acc);
    be[t] = acc;   // byte_e[b][k][e2], flat k*20+e2
  }
  __syncthreads();
  if (t < 20) {
    float acc = enc_b[t];
#pragma unroll
    for (int d = 0; d < 80; d++) acc = fmaf(enc_W[t * 80 + d], be[d], acc);
    fr[t] = 1.0f / (1.0f + __expf(-acc));              // fe
  } else if (t < 60) {
    fr[t] = ws[OF_DIST + b * 40 + (t - 20)] * (1.0f / 4096.0f);  // dist_vector
  }
  __syncthreads();
  if (t < 10) {
    float acc = d1_b[t];
#pragma unroll
    for (int d = 0; d < 60; d++) acc = fmaf(d1_W[t * 60 + d], fr[d], acc);
    r1[t] = acc > 0.f ? acc : 0.f;
  }
  __syncthreads();
  if (t < 2) {
    float acc = d2_b[t];
#pragma unroll
    for (int r = 0; r < 10; r++) acc = fmaf(d2_W[t * 10 + r], r1[r], acc);
    out[131072 + t * 64 + b] = acc;
  }
}

extern "C" void kernel_launch(void* const* d_in, const int* in_sizes, int n_in,
                              void* d_out, int out_size, void* d_ws, size_t ws_size,
                              hipStream_t stream) {
  const int*   inp    = (const int*)  d_in[0];
  const float* h0     = (const float*)d_in[1];
  const float* c0     = (const float*)d_in[2];
  const float* pc_emb = (const float*)d_in[3];
  const float* addr_e = (const float*)d_in[4];
  const float* enc_W  = (const float*)d_in[5];
  const float* enc_b  = (const float*)d_in[6];
  const float* W_ih   = (const float*)d_in[7];
  const float* W_hh   = (const float*)d_in[8];
  const float* b_ih   = (const float*)d_in[9];
  const float* b_hh   = (const float*)d_in[10];
  const float* dec_W  = (const float*)d_in[11];
  const float* dec_b  = (const float*)d_in[12];
  const float* d1_W   = (const float*)d_in[13];
  const float* d1_b   = (const float*)d_in[14];
  const float* d2_W   = (const float*)d_in[15];
  const float* d2_b   = (const float*)d_in[16];
  float* out = (float*)d_out;
  float* ws  = (float*)d_ws;

  if (ws_size < WS_NEEDED_FLOATS * sizeof(float)) return;  // constant per session; avoids OOB

  hipLaunchKernelGGL(k_init, dim3(19), dim3(256), 0, stream,
                     pc_emb, addr_e, enc_W, b_ih, b_hh, ws);
  hipLaunchKernelGGL(k_embed, dim3(1024), dim3(256), 0, stream, inp, enc_b, W_ih, ws);
  hipLaunchKernelGGL(k_lstm, dim3(64), dim3(64), 0, stream, h0, c0, W_hh, ws);
  hipLaunchKernelGGL(k_dec, dim3(256), dim3(256), 0, stream, dec_W, dec_b, out, ws);
  hipLaunchKernelGGL(k_freq, dim3(64), dim3(128), 0, stream,
                     addr_e, enc_W, enc_b, d1_W, d1_b, d2_W, d2_b, out, ws);
}

// Round 2
// 1241.395 us; speedup vs baseline: 1.1455x; 1.1455x over previous
//
#include <hip/hip_runtime.h>
#include <math.h>

#define BB 64
#define SS 4096
// ws layout (float offsets)
#define OF_G    0              // 2*4*256*20 = 40960 floats
#define OF_BG   40960          // 80
#define OF_DIST 41056          // 64*40 = 2560
#define OF_HFIN 43616          // 64*20 = 1280
#define OF_X    45056          // 64*4096*80 = 20971520
#define WS_NEEDED_FLOATS (OF_X + (size_t)BB * SS * 80)

typedef float v2f __attribute__((ext_vector_type(2)));

__device__ __forceinline__ float fast_rcp(float x) { return __builtin_amdgcn_rcpf(x); }
__device__ __forceinline__ float sigm_fast(float x) { return fast_rcp(1.0f + __expf(-x)); }
__device__ __forceinline__ float tanh_fast(float x) { return 1.0f - 2.0f * fast_rcp(1.0f + __expf(2.0f * x)); }
__device__ __forceinline__ float sigm_prec(float x) { return 1.0f / (1.0f + __expf(-x)); }

// ---------------- K0: G tables + combined bias + zero dist accumulator ----------
__global__ __launch_bounds__(256) void k_init(const float* __restrict__ pc_emb,
    const float* __restrict__ addr_emb, const float* __restrict__ enc_W,
    const float* __restrict__ b_ih, const float* __restrict__ b_hh,
    float* __restrict__ ws) {
  int gid = blockIdx.x * 256 + threadIdx.x;
  if (gid < 2048) {
    int t = gid >> 10;          // stream: 0=pc, 1=addr
    int i = (gid >> 8) & 3;     // byte position
    int byt = gid & 255;
    const float* tab = (t == 0 ? pc_emb : addr_emb) + (i * 256 + byt) * 20;
    float tv[20];
#pragma unroll
    for (int m = 0; m < 20; m++) tv[m] = tab[m];
    float* Grow = ws + OF_G + gid * 20;
#pragma unroll
    for (int j = 0; j < 20; j++) {
      float acc = 0.f;
#pragma unroll
      for (int m = 0; m < 20; m++) acc = fmaf(enc_W[j * 80 + i * 20 + m], tv[m], acc);
      Grow[j] = acc;
    }
  } else if (gid < 2048 + 80) {
    int g = gid - 2048;
    ws[OF_BG + g] = b_ih[g] + b_hh[g];
  } else if (gid < 2048 + 80 + 2560) {
    ws[OF_DIST + (gid - 2128)] = 0.f;
  }
}

// ---------------- K1: embed + encoder + X precompute (coalesced) + dist ---------
// 1 wave per block; wave = 64 consecutive tokens of one batch item.
__global__ __launch_bounds__(64) void k_embed(const int* __restrict__ inp,
    const float* __restrict__ enc_b, const float* __restrict__ W_ih,
    float* __restrict__ ws) {
  __shared__ float lds[80 * 65];   // X-tile staged (padded); reused for e-transpose
  int b = blockIdx.x >> 6;
  int schunk = (blockIdx.x & 63) << 6;
  int t = threadIdx.x;
  int s = schunk + t;
  unsigned v0 = (unsigned)inp[(b * SS + s) * 2 + 0];
  unsigned v1 = (unsigned)inp[(b * SS + s) * 2 + 1];
  const float* G = ws + OF_G;
  float e[40];
#pragma unroll
  for (int st = 0; st < 2; st++) {
    unsigned v = (st == 0) ? v0 : v1;
    int by0 = (int)(v >> 24);
    int by1 = (int)((v >> 16) & 255u);
    int by2 = (int)((v >> 8) & 255u);
    int by3 = (int)(v & 255u);
    const float* G0 = G + ((st * 4 + 0) * 256 + by0) * 20;
    const float* G1 = G + ((st * 4 + 1) * 256 + by1) * 20;
    const float* G2 = G + ((st * 4 + 2) * 256 + by2) * 20;
    const float* G3 = G + ((st * 4 + 3) * 256 + by3) * 20;
#pragma unroll
    for (int j = 0; j < 20; j++) {
      float y = enc_b[j] + G0[j] + G1[j] + G2[j] + G3[j];
      e[st * 20 + j] = sigm_prec(y);
    }
  }
  // gates: W_ih rows are wave-uniform -> scalar loads; e in VGPRs; stage to LDS
  const float* bg = ws + OF_BG;
#pragma unroll 4
  for (int g = 0; g < 80; g++) {
    float a = bg[g];
#pragma unroll
    for (int d = 0; d < 40; d++) a = fmaf(W_ih[g * 40 + d], e[d], a);
    lds[g * 65 + t] = a;          // banks (g+t)%32: conflict-free
  }
  __syncthreads();
  // coalesced flush: float4 per (token, j) in LSTM read layout [tok][j][q]
  float4* XF4 = (float4*)(ws + OF_X) + (size_t)(b * SS + schunk) * 20;
#pragma unroll
  for (int it = 0; it < 20; it++) {
    int q = it * 64 + t;          // 0..1279
    int tok = q / 20;
    int jf = q - tok * 20;
    float4 vv;
    vv.x = lds[(0  + jf) * 65 + tok];
    vv.y = lds[(20 + jf) * 65 + tok];
    vv.z = lds[(40 + jf) * 65 + tok];
    vv.w = lds[(60 + jf) * 65 + tok];
    XF4[q] = vv;
  }
  __syncthreads();
  // dist partial sums: transpose e to LDS, 40 lanes column-sum, 1 atomic each
  float* eT = lds;                // 40*66 = 2640 <= 5200
#pragma unroll
  for (int d = 0; d < 40; d++) eT[d * 66 + t] = e[d];
  __syncthreads();
  if (t < 40) {
    float ssum = 0.f;
#pragma unroll 8
    for (int tok = 0; tok < 64; tok++) ssum += eT[t * 66 + tok];
    atomicAdd(ws + OF_DIST + b * 40 + t, ssum);
  }
}

// ---------------- K2: sequential LSTM, one wave per batch item ------------------
// lanes (j, j+32) split the m-dot in half; packed fp32 FMA over gate pairs.
__global__ __launch_bounds__(64) void k_lstm(const float* __restrict__ h0,
    const float* __restrict__ c0, const float* __restrict__ W_hh,
    float* __restrict__ ws) {
  int b = blockIdx.x;
  int l = threadIdx.x;
  int jj = l & 31;
  int j = jj < 20 ? jj : 19;      // lanes >=20 in each half mirror j=19 harmlessly
  int sp = l >> 5;                // 0: m=0..9, 1: m=10..19
  int m0 = sp * 10;
  v2f wif[10], wgo[10];
#pragma unroll
  for (int m = 0; m < 10; m++) {
    wif[m] = (v2f){W_hh[(0 * 20 + j) * 20 + m0 + m], W_hh[(1 * 20 + j) * 20 + m0 + m]};
    wgo[m] = (v2f){W_hh[(2 * 20 + j) * 20 + m0 + m], W_hh[(3 * 20 + j) * 20 + m0 + m]};
  }
  float h = h0[b * 20 + j];
  float c = c0[b * 20 + j];
  const float4* Xp = (const float4*)(ws + OF_X) + (size_t)b * SS * 20 + j;
  float4 xb[8];
#pragma unroll
  for (int p = 0; p < 8; p++) xb[p] = Xp[(size_t)p * 20];
  for (int s = 0; s < SS; s += 8) {
#pragma unroll
    for (int u = 0; u < 8; u++) {
      float4 x4 = xb[u];
      int sn = s + u + 8; if (sn > SS - 1) sn = SS - 1;
      xb[u] = Xp[(size_t)sn * 20];
      // each half initializes its own x components exactly once
      v2f aif = sp ? (v2f){0.f, 0.f} : (v2f){x4.x, x4.y};
      v2f ago = sp ? (v2f){x4.z, x4.w} : (v2f){0.f, 0.f};
#pragma unroll
      for (int m = 0; m < 10; m++) {
        float hm = __shfl(h, m0 + m, 64);     // ds_bpermute, per-half m-range
        v2f hv = (v2f){hm, hm};
        aif = __builtin_elementwise_fma(wif[m], hv, aif);
        ago = __builtin_elementwise_fma(wgo[m], hv, ago);
      }
      // combine halves (symmetric add -> both lanes get bit-identical sums)
      aif.x += __shfl_xor(aif.x, 32);
      aif.y += __shfl_xor(aif.y, 32);
      ago.x += __shfl_xor(ago.x, 32);
      ago.y += __shfl_xor(ago.y, 32);
      float si = sigm_fast(aif.x);
      float sf = sigm_fast(aif.y);
      float tg = tanh_fast(ago.x);
      float so = sigm_fast(ago.y);
      c = fmaf(sf, c, si * tg);
      h = so * tanh_fast(c);
    }
  }
  if (l < 20) ws[OF_HFIN + b * 20 + l] = h;
}

// ---------------- K3: decoder heads + softmax over batch axis -------------------
__global__ __launch_bounds__(256) void k_dec(const float* __restrict__ dec_W,
    const float* __restrict__ dec_b, float* __restrict__ out,
    const float* __restrict__ ws) {
  int wid = blockIdx.x * 4 + (threadIdx.x >> 6);  // (k,v) pair id, 0..1023
  int lane = threadIdx.x & 63;                    // = batch index b
  int k = wid >> 8;
  int v = wid & 255;
  const float* hp = ws + OF_HFIN + lane * 20;
  const float* wp = dec_W + (k * 256 + v) * 20;
  float l = dec_b[k * 256 + v];
#pragma unroll
  for (int jj = 0; jj < 20; jj++) l = fmaf(hp[jj], wp[jj], l);
  float x = l / 0.001f;
  float mx = x;
#pragma unroll
  for (int off = 32; off; off >>= 1) mx = fmaxf(mx, __shfl_xor(mx, off));
  float ex = __expf(x - mx);
  float sm = ex;
#pragma unroll
  for (int off = 32; off; off >>= 1) sm += __shfl_xor(sm, off);
  float p = ex / sm;
  int oidx = (k * 64 + lane) * 256 + v;
  out[oidx] = p;            // probs
  out[65536 + oidx] = l;    // logits
}

// ---------------- K4: byte_e = probs @ addr_emb, encoder, MLP head --------------
__global__ __launch_bounds__(128) void k_freq(const float* __restrict__ addr_emb,
    const float* __restrict__ enc_W, const float* __restrict__ enc_b,
    const float* __restrict__ d1_W, const float* __restrict__ d1_b,
    const float* __restrict__ d2_W, const float* __restrict__ d2_b,
    float* __restrict__ out, const float* __restrict__ ws) {
  __shared__ float be[80];
  __shared__ float fr[60];
  __shared__ float r1[10];
  int b = blockIdx.x;
  int t = threadIdx.x;
  if (t < 80) {
    int k = t / 20, e2 = t % 20;
    const float* pp = out + (k * 64 + b) * 256;        // probs[k,0,b,:]
    const float* ap = addr_emb + (k * 256) * 20 + e2;
    float acc = 0.f;
    for (int v = 0; v < 256; v++) acc = fmaf(pp[v], ap[v * 20], acc);
    be[t] = acc;   // byte_e[b][k][e2], flat k*20+e2
  }
  __syncthreads();
  if (t < 20) {
    float acc = enc_b[t];
#pragma unroll
    for (int d = 0; d < 80; d++) acc = fmaf(enc_W[t * 80 + d], be[d], acc);
    fr[t] = 1.0f / (1.0f + __expf(-acc));              // fe
  } else if (t < 60) {
    fr[t] = ws[OF_DIST + b * 40 + (t - 20)] * (1.0f / 4096.0f);  // dist_vector
  }
  __syncthreads();
  if (t < 10) {
    float acc = d1_b[t];
#pragma unroll
    for (int d = 0; d < 60; d++) acc = fmaf(d1_W[t * 60 + d], fr[d], acc);
    r1[t] = acc > 0.f ? acc : 0.f;
  }
  __syncthreads();
  if (t < 2) {
    float acc = d2_b[t];
#pragma unroll
    for (int r = 0; r < 10; r++) acc = fmaf(d2_W[t * 10 + r], r1[r], acc);
    out[131072 + t * 64 + b] = acc;
  }
}

extern "C" void kernel_launch(void* const* d_in, const int* in_sizes, int n_in,
                              void* d_out, int out_size, void* d_ws, size_t ws_size,
                              hipStream_t stream) {
  const int*   inp    = (const int*)  d_in[0];
  const float* h0     = (const float*)d_in[1];
  const float* c0     = (const float*)d_in[2];
  const float* pc_emb = (const float*)d_in[3];
  const float* addr_e = (const float*)d_in[4];
  const float* enc_W  = (const float*)d_in[5];
  const float* enc_b  = (const float*)d_in[6];
  const float* W_ih   = (const float*)d_in[7];
  const float* W_hh   = (const float*)d_in[8];
  const float* b_ih   = (const float*)d_in[9];
  const float* b_hh   = (const float*)d_in[10];
  const float* dec_W  = (const float*)d_in[11];
  const float* dec_b  = (const float*)d_in[12];
  const float* d1_W   = (const float*)d_in[13];
  const float* d1_b   = (const float*)d_in[14];
  const float* d2_W   = (const float*)d_in[15];
  const float* d2_b   = (const float*)d_in[16];
  float* out = (float*)d_out;
  float* ws  = (float*)d_ws;

  if (ws_size < WS_NEEDED_FLOATS * sizeof(float)) return;

  hipLaunchKernelGGL(k_init, dim3(19), dim3(256), 0, stream,
                     pc_emb, addr_e, enc_W, b_ih, b_hh, ws);
  hipLaunchKernelGGL(k_embed, dim3(4096), dim3(64), 0, stream, inp, enc_b, W_ih, ws);
  hipLaunchKernelGGL(k_lstm, dim3(64), dim3(64), 0, stream, h0, c0, W_hh, ws);
  hipLaunchKernelGGL(k_dec, dim3(256), dim3(256), 0, stream, dec_W, dec_b, out, ws);
  hipLaunchKernelGGL(k_freq, dim3(64), dim3(128), 0, stream,
                     addr_e, enc_W, enc_b, d1_W, d1_b, d2_W, d2_b, out, ws);
}

// Round 3
// 1073.965 us; speedup vs baseline: 1.3241x; 1.1559x over previous
//
#include <hip/hip_runtime.h>
#include <math.h>

#define BB 64
#define SS 4096
// ws layout (float offsets)
#define OF_G    0              // 2*4*256*20 = 40960 floats
#define OF_BG   40960          // 80
#define OF_DIST 41056          // 64*40 = 2560
#define OF_HFIN 43616          // 64*20 = 1280
#define OF_X    45056          // 64*4096*80 = 20971520
#define WS_NEEDED_FLOATS (OF_X + (size_t)BB * SS * 80)

#define L2E 1.4426950408889634f

typedef float v2f __attribute__((ext_vector_type(2)));

__device__ __forceinline__ float fast_rcp(float x) { return __builtin_amdgcn_rcpf(x); }
__device__ __forceinline__ float fast_exp2(float x) { return __builtin_amdgcn_exp2f(x); }
__device__ __forceinline__ float sigm_prec(float x) { return 1.0f / (1.0f + __expf(-x)); }

// ---------------- K0: G tables + combined bias + zero dist accumulator ----------
__global__ __launch_bounds__(256) void k_init(const float* __restrict__ pc_emb,
    const float* __restrict__ addr_emb, const float* __restrict__ enc_W,
    const float* __restrict__ b_ih, const float* __restrict__ b_hh,
    float* __restrict__ ws) {
  int gid = blockIdx.x * 256 + threadIdx.x;
  if (gid < 2048) {
    int t = gid >> 10;          // stream: 0=pc, 1=addr
    int i = (gid >> 8) & 3;     // byte position
    int byt = gid & 255;
    const float* tab = (t == 0 ? pc_emb : addr_emb) + (i * 256 + byt) * 20;
    float tv[20];
#pragma unroll
    for (int m = 0; m < 20; m++) tv[m] = tab[m];
    float* Grow = ws + OF_G + gid * 20;
#pragma unroll
    for (int j = 0; j < 20; j++) {
      float acc = 0.f;
#pragma unroll
      for (int m = 0; m < 20; m++) acc = fmaf(enc_W[j * 80 + i * 20 + m], tv[m], acc);
      Grow[j] = acc;
    }
  } else if (gid < 2048 + 80) {
    int g = gid - 2048;
    ws[OF_BG + g] = b_ih[g] + b_hh[g];
  } else if (gid < 2048 + 80 + 2560) {
    ws[OF_DIST + (gid - 2128)] = 0.f;
  }
}

// ---------------- K1: embed + encoder + X precompute (coalesced) + dist ---------
// 1 wave per block; wave = 64 consecutive tokens of one batch item.
// X gate pre-activations are PRE-SCALED: i,f,o by -log2e; g by +2*log2e, so the
// LSTM activations need no multiply before exp2.
__global__ __launch_bounds__(64) void k_embed(const int* __restrict__ inp,
    const float* __restrict__ enc_b, const float* __restrict__ W_ih,
    float* __restrict__ ws) {
  __shared__ float lds[80 * 65];   // X-tile staged (padded); reused for e-transpose
  int b = blockIdx.x >> 6;
  int schunk = (blockIdx.x & 63) << 6;
  int t = threadIdx.x;
  int s = schunk + t;
  unsigned v0 = (unsigned)inp[(b * SS + s) * 2 + 0];
  unsigned v1 = (unsigned)inp[(b * SS + s) * 2 + 1];
  const float* G = ws + OF_G;
  float e[40];
#pragma unroll
  for (int st = 0; st < 2; st++) {
    unsigned v = (st == 0) ? v0 : v1;
    int by0 = (int)(v >> 24);
    int by1 = (int)((v >> 16) & 255u);
    int by2 = (int)((v >> 8) & 255u);
    int by3 = (int)(v & 255u);
    const float* G0 = G + ((st * 4 + 0) * 256 + by0) * 20;
    const float* G1 = G + ((st * 4 + 1) * 256 + by1) * 20;
    const float* G2 = G + ((st * 4 + 2) * 256 + by2) * 20;
    const float* G3 = G + ((st * 4 + 3) * 256 + by3) * 20;
#pragma unroll
    for (int j = 0; j < 20; j++) {
      float y = enc_b[j] + G0[j] + G1[j] + G2[j] + G3[j];
      e[st * 20 + j] = sigm_prec(y);
    }
  }
  // gates: W_ih rows are wave-uniform -> scalar loads; e in VGPRs; stage to LDS
  const float* bg = ws + OF_BG;
#pragma unroll 4
  for (int g = 0; g < 80; g++) {
    float a = bg[g];
#pragma unroll
    for (int d = 0; d < 40; d++) a = fmaf(W_ih[g * 40 + d], e[d], a);
    lds[g * 65 + t] = a;          // banks (g+t)%32: conflict-free
  }
  __syncthreads();
  // coalesced flush: float4 per (token, j), pre-scaled for exp2-based gates
  float4* XF4 = (float4*)(ws + OF_X) + (size_t)(b * SS + schunk) * 20;
#pragma unroll
  for (int it = 0; it < 20; it++) {
    int q = it * 64 + t;          // 0..1279
    int tok = q / 20;
    int jf = q - tok * 20;
    float4 vv;
    vv.x = lds[(0  + jf) * 65 + tok] * (-L2E);        // i
    vv.y = lds[(20 + jf) * 65 + tok] * (-L2E);        // f
    vv.z = lds[(40 + jf) * 65 + tok] * (2.0f * L2E);  // g
    vv.w = lds[(60 + jf) * 65 + tok] * (-L2E);        // o
    XF4[q] = vv;
  }
  __syncthreads();
  // dist partial sums: transpose e to LDS, 40 lanes column-sum, 1 atomic each
  float* eT = lds;                // 40*66 = 2640 <= 5200
#pragma unroll
  for (int d = 0; d < 40; d++) eT[d * 66 + t] = e[d];
  __syncthreads();
  if (t < 40) {
    float ssum = 0.f;
#pragma unroll 8
    for (int tok = 0; tok < 64; tok++) ssum += eT[t * 66 + tok];
    atomicAdd(ws + OF_DIST + b * 40 + t, ssum);
  }
}

// ---------------- K2: sequential LSTM, one wave per batch item ------------------
// Zero LDS hops on the critical path: h broadcast by v_readlane -> SGPR; each
// lane does the FULL 20-deep dot for its (i,f)/(g,o) packed gate pairs.
__global__ __launch_bounds__(64) void k_lstm(const float* __restrict__ h0,
    const float* __restrict__ c0, const float* __restrict__ W_hh,
    float* __restrict__ ws) {
  int b = blockIdx.x;
  int l = threadIdx.x;
  int j = (l & 31) < 20 ? (l & 31) : 19;  // lanes >=20 mirror j=19 harmlessly
  v2f wif[20], wgo[20];
#pragma unroll
  for (int m = 0; m < 20; m++) {
    wif[m] = (v2f){W_hh[(0 * 20 + j) * 20 + m] * (-L2E),
                   W_hh[(1 * 20 + j) * 20 + m] * (-L2E)};
    wgo[m] = (v2f){W_hh[(2 * 20 + j) * 20 + m] * (2.0f * L2E),
                   W_hh[(3 * 20 + j) * 20 + m] * (-L2E)};
  }
  float h = h0[b * 20 + j];
  float c = c0[b * 20 + j];
  const float4* Xp = (const float4*)(ws + OF_X) + (size_t)b * SS * 20 + j;
  float4 xb[8];
#pragma unroll
  for (int p = 0; p < 8; p++) xb[p] = Xp[(size_t)p * 20];
  for (int s = 0; s < SS; s += 8) {
#pragma unroll
    for (int u = 0; u < 8; u++) {
      float4 x4 = xb[u];
      int sn = s + u + 8; if (sn > SS - 1) sn = SS - 1;
      xb[u] = Xp[(size_t)sn * 20];
      v2f aif = (v2f){x4.x, x4.y};
      v2f ago = (v2f){x4.z, x4.w};
#pragma unroll
      for (int m = 0; m < 20; m++) {
        float hm = __int_as_float(__builtin_amdgcn_readlane(__float_as_int(h), m));
        v2f hv = (v2f){hm, hm};
        aif = __builtin_elementwise_fma(wif[m], hv, aif);
        ago = __builtin_elementwise_fma(wgo[m], hv, ago);
      }
      // pre-scaled gates: sigmoid(x) = rcp(1+exp2(-x*log2e)); tanh(x)=1-2*rcp(1+exp2(2x*log2e))
      float si = fast_rcp(1.0f + fast_exp2(aif.x));
      float sf = fast_rcp(1.0f + fast_exp2(aif.y));
      float tg = fmaf(-2.0f, fast_rcp(1.0f + fast_exp2(ago.x)), 1.0f);
      float so = fast_rcp(1.0f + fast_exp2(ago.y));
      c = fmaf(sf, c, si * tg);
      float tc = fmaf(-2.0f, fast_rcp(1.0f + fast_exp2(c * (2.0f * L2E))), 1.0f);
      h = so * tc;
    }
  }
  if (l < 20) ws[OF_HFIN + b * 20 + l] = h;
}

// ---------------- K3: decoder heads + softmax over batch axis -------------------
__global__ __launch_bounds__(256) void k_dec(const float* __restrict__ dec_W,
    const float* __restrict__ dec_b, float* __restrict__ out,
    const float* __restrict__ ws) {
  int wid = blockIdx.x * 4 + (threadIdx.x >> 6);  // (k,v) pair id, 0..1023
  int lane = threadIdx.x & 63;                    // = batch index b
  int k = wid >> 8;
  int v = wid & 255;
  const float* hp = ws + OF_HFIN + lane * 20;
  const float* wp = dec_W + (k * 256 + v) * 20;
  float l = dec_b[k * 256 + v];
#pragma unroll
  for (int jj = 0; jj < 20; jj++) l = fmaf(hp[jj], wp[jj], l);
  float x = l / 0.001f;
  float mx = x;
#pragma unroll
  for (int off = 32; off; off >>= 1) mx = fmaxf(mx, __shfl_xor(mx, off));
  float ex = __expf(x - mx);
  float sm = ex;
#pragma unroll
  for (int off = 32; off; off >>= 1) sm += __shfl_xor(sm, off);
  float p = ex / sm;
  int oidx = (k * 64 + lane) * 256 + v;
  out[oidx] = p;            // probs
  out[65536 + oidx] = l;    // logits
}

// ---------------- K4: byte_e = probs @ addr_emb, encoder, MLP head --------------
__global__ __launch_bounds__(128) void k_freq(const float* __restrict__ addr_emb,
    const float* __restrict__ enc_W, const float* __restrict__ enc_b,
    const float* __restrict__ d1_W, const float* __restrict__ d1_b,
    const float* __restrict__ d2_W, const float* __restrict__ d2_b,
    float* __restrict__ out, const float* __restrict__ ws) {
  __shared__ float be[80];
  __shared__ float fr[60];
  __shared__ float r1[10];
  int b = blockIdx.x;
  int t = threadIdx.x;
  if (t < 80) {
    int k = t / 20, e2 = t % 20;
    const float* pp = out + (k * 64 + b) * 256;        // probs[k,0,b,:]
    const float* ap = addr_emb + (k * 256) * 20 + e2;
    float acc = 0.f;
    for (int v = 0; v < 256; v++) acc = fmaf(pp[v], ap[v * 20], acc);
    be[t] = acc;   // byte_e[b][k][e2], flat k*20+e2
  }
  __syncthreads();
  if (t < 20) {
    float acc = enc_b[t];
#pragma unroll
    for (int d = 0; d < 80; d++) acc = fmaf(enc_W[t * 80 + d], be[d], acc);
    fr[t] = 1.0f / (1.0f + __expf(-acc));              // fe
  } else if (t < 60) {
    fr[t] = ws[OF_DIST + b * 40 + (t - 20)] * (1.0f / 4096.0f);  // dist_vector
  }
  __syncthreads();
  if (t < 10) {
    float acc = d1_b[t];
#pragma unroll
    for (int d = 0; d < 60; d++) acc = fmaf(d1_W[t * 60 + d], fr[d], acc);
    r1[t] = acc > 0.f ? acc : 0.f;
  }
  __syncthreads();
  if (t < 2) {
    float acc = d2_b[t];
#pragma unroll
    for (int r = 0; r < 10; r++) acc = fmaf(d2_W[t * 10 + r], r1[r], acc);
    out[131072 + t * 64 + b] = acc;
  }
}

extern "C" void kernel_launch(void* const* d_in, const int* in_sizes, int n_in,
                              void* d_out, int out_size, void* d_ws, size_t ws_size,
                              hipStream_t stream) {
  const int*   inp    = (const int*)  d_in[0];
  const float* h0     = (const float*)d_in[1];
  const float* c0     = (const float*)d_in[2];
  const float* pc_emb = (const float*)d_in[3];
  const float* addr_e = (const float*)d_in[4];
  const float* enc_W  = (const float*)d_in[5];
  const float* enc_b  = (const float*)d_in[6];
  const float* W_ih   = (const float*)d_in[7];
  const float* W_hh   = (const float*)d_in[8];
  const float* b_ih   = (const float*)d_in[9];
  const float* b_hh   = (const float*)d_in[10];
  const float* dec_W  = (const float*)d_in[11];
  const float* dec_b  = (const float*)d_in[12];
  const float* d1_W   = (const float*)d_in[13];
  const float* d1_b   = (const float*)d_in[14];
  const float* d2_W   = (const float*)d_in[15];
  const float* d2_b   = (const float*)d_in[16];
  float* out = (float*)d_out;
  float* ws  = (float*)d_ws;

  if (ws_size < WS_NEEDED_FLOATS * sizeof(float)) return;

  hipLaunchKernelGGL(k_init, dim3(19), dim3(256), 0, stream,
                     pc_emb, addr_e, enc_W, b_ih, b_hh, ws);
  hipLaunchKernelGGL(k_embed, dim3(4096), dim3(64), 0, stream, inp, enc_b, W_ih, ws);
  hipLaunchKernelGGL(k_lstm, dim3(64), dim3(64), 0, stream, h0, c0, W_hh, ws);
  hipLaunchKernelGGL(k_dec, dim3(256), dim3(256), 0, stream, dec_W, dec_b, out, ws);
  hipLaunchKernelGGL(k_freq, dim3(64), dim3(128), 0, stream,
                     addr_e, enc_W, enc_b, d1_W, d1_b, d2_W, d2_b, out, ws);
}